// Round 1
// baseline (61.495 us; speedup 1.0000x reference)
//
#include <hip/hip_runtime.h>
#include <hip/hip_bf16.h>
#include <cstdint>
#include <cstddef>

typedef short short8 __attribute__((ext_vector_type(8)));
typedef float f32x4 __attribute__((ext_vector_type(4)));

constexpr int Nrows = 8192;   // rows of a
constexpr int Mrows = 8192;   // rows of b
constexpr int Dim   = 64;     // feature dim (K)

// ---------------------------------------------------------------------------
// Kernel 1: per-row L2 norm, scale row to unit length, cast to bf16 (RNE).
// 16 lanes per row, each lane owns one float4 (16*4 = 64 elements).
// ---------------------------------------------------------------------------
__global__ __launch_bounds__(256) void cos_norm_scale(
    const float* __restrict__ a, const float* __restrict__ b,
    short* __restrict__ as_, short* __restrict__ bs_) {
  int gid = blockIdx.x * 256 + threadIdx.x;
  int row = gid >> 4;      // 16 threads per row
  int sub = gid & 15;      // which float4 of the row
  const float* src = a;
  short* dst = as_;
  if (row >= Nrows) { src = b; dst = bs_; row -= Nrows; }

  float4 v = reinterpret_cast<const float4*>(src + (size_t)row * Dim)[sub];
  float ss = v.x * v.x + v.y * v.y + v.z * v.z + v.w * v.w;
  // butterfly reduce across the 16 lanes owning this row (stays in-group)
  ss += __shfl_xor(ss, 1);
  ss += __shfl_xor(ss, 2);
  ss += __shfl_xor(ss, 4);
  ss += __shfl_xor(ss, 8);
  float scale = rsqrtf(ss);

  float sv[4] = {v.x * scale, v.y * scale, v.z * scale, v.w * scale};
  short4 o;
  short* op = reinterpret_cast<short*>(&o);
#pragma unroll
  for (int i = 0; i < 4; ++i) {
    uint32_t u = __float_as_uint(sv[i]);
    u += 0x7fffu + ((u >> 16) & 1u);   // round-to-nearest-even to bf16
    op[i] = (short)(u >> 16);
  }
  reinterpret_cast<short4*>(dst + (size_t)row * Dim)[sub] = o;
}

// ---------------------------------------------------------------------------
// Kernel 2: C = A_unit @ B_unit^T via mfma_f32_16x16x32_bf16.
// Block = 256 threads = 4 waves; block tile 128x128; each wave owns a 64x64
// quadrant (4x4 fragments of 16x16). K=64 -> 2 MFMA k-steps per fragment.
// A,B are tiny (1 MB each) and L2/L3-resident: fragments load straight from
// global, no LDS, no barriers.
//
// Fragment layouts (gfx950, HW-verified per guide §3):
//   A/B in : lane l holds 8 contiguous k-elems: row=l&15, k=(l>>4)*8 .. +7
//   C/D out: col = l&15, row = (l>>4)*4 + reg
// ---------------------------------------------------------------------------
__global__ __launch_bounds__(256) void cos_gemm(
    const short* __restrict__ A, const short* __restrict__ B,
    float* __restrict__ C) {
  int tile = blockIdx.x;
  int tm = tile >> 6;          // 64 tiles along M-of-output (a rows)
  int tn = tile & 63;          // 64 tiles along N-of-output (b rows)
  int wid  = threadIdx.x >> 6; // 0..3
  int lane = threadIdx.x & 63;
  int wr = wid >> 1, wc = wid & 1;

  int R0 = tm * 128 + wr * 64; // output row base for this wave
  int C0 = tn * 128 + wc * 64; // output col base for this wave

  int lrow = lane & 15;
  int lk8  = (lane >> 4) * 8;

  f32x4 acc[4][4] = {};

#pragma unroll
  for (int s = 0; s < 2; ++s) {        // K steps of 32
    short8 af[4], bf[4];
#pragma unroll
    for (int i = 0; i < 4; ++i)
      af[i] = *reinterpret_cast<const short8*>(
          A + (size_t)(R0 + i * 16 + lrow) * Dim + s * 32 + lk8);
#pragma unroll
    for (int j = 0; j < 4; ++j)
      bf[j] = *reinterpret_cast<const short8*>(
          B + (size_t)(C0 + j * 16 + lrow) * Dim + s * 32 + lk8);
#pragma unroll
    for (int i = 0; i < 4; ++i)
#pragma unroll
      for (int j = 0; j < 4; ++j)
        acc[i][j] = __builtin_amdgcn_mfma_f32_16x16x32_bf16(
            af[i], bf[j], acc[i][j], 0, 0, 0);
  }

  int crow = (lane >> 4) * 4;
  int ccol = lane & 15;
#pragma unroll
  for (int i = 0; i < 4; ++i) {
#pragma unroll
    for (int j = 0; j < 4; ++j) {
      float* p = C + (size_t)(R0 + i * 16 + crow) * Mrows + (C0 + j * 16 + ccol);
#pragma unroll
      for (int r = 0; r < 4; ++r)
        p[(size_t)r * Mrows] = acc[i][j][r];
    }
  }
}

// ---------------------------------------------------------------------------
extern "C" void kernel_launch(void* const* d_in, const int* in_sizes, int n_in,
                              void* d_out, int out_size, void* d_ws, size_t ws_size,
                              hipStream_t stream) {
  const float* a = (const float*)d_in[0];
  const float* b = (const float*)d_in[1];
  float* out = (float*)d_out;

  short* as_ = (short*)d_ws;                       // 8192*64 bf16 = 1 MB
  short* bs_ = as_ + (size_t)Nrows * Dim;          // next 1 MB

  // (8192+8192) rows * 16 threads/row / 256 threads/block = 1024 blocks
  cos_norm_scale<<<1024, 256, 0, stream>>>(a, b, as_, bs_);

  // (8192/128)^2 = 4096 tiles
  cos_gemm<<<4096, 256, 0, stream>>>(as_, bs_, out);
}